// Round 8
// baseline (7124.862 us; speedup 1.0000x reference)
//
#include <hip/hip_runtime.h>
#include <cstdint>
#include <cstddef>

// RecurrentDecoder: 128 sequential GRU steps fused via x_t = h_t @ W_dec^T
// => gates = h @ W_eff^T (4096 gate cols + 256 decode cols), one GEMM/step.
// FP32 in/out; internal GEMM fp16 MFMA; h carried fp32 (+fp16 mirror for A).
// Round 8: persistent flag-sync kernel (R7 design) with LDS cut to 34816 B
// (BK=32 dbuf) — the size R4's cooperative launch demonstrably accepted;
// R7's 69632 B exceeded the 64 KiB coop-launch validation limit and the
// launch silently failed. Fallback to per-step launches if coop errors.
// 256 blocks = 8 mt x 32 cb; block tile [128 x 144], 4 waves (2x2).

#define HD 1024
#define BD 1024
#define OD 256
#define TS 128

typedef _Float16 f16x8 __attribute__((ext_vector_type(8)));
typedef float f32x4 __attribute__((ext_vector_type(4)));

__device__ __forceinline__ void gl_lds16(const void* g, void* l) {
  auto gp = reinterpret_cast<const __attribute__((address_space(1))) unsigned int*>(
      reinterpret_cast<uintptr_t>(g));
  auto lp = reinterpret_cast<__attribute__((address_space(3))) unsigned int*>(
      reinterpret_cast<uintptr_t>(l));
  __builtin_amdgcn_global_load_lds(gp, lp, 16, 0, 0);
}

// ---------------- prep: build W_ws [32 cb][144 rows][1024 k] fp16 ----------------
// slab row rr<128: section s=rr>>5 (0:r, 1:z, 2:i_n, 3:h_n), wcol=(rr>>4)&1, p=rr&15,
//   gate col j = cb*32 + wcol*16 + p.
//   s=0: Wc[j]+Whh[j]; s=1: Wc[1024+j]+Whh[1024+j]; s=2: Wc[2048+j]; s=3: Whh[2048+j]
// rr 128..135: W_dec row 8*cb + rr-128 ; rr 136..143: zeros.  (Wc = W_ih @ W_dec, fp32 accum)
__global__ __launch_bounds__(256) void prep_w(
    const float* __restrict__ Wih,   // [3072][256]
    const float* __restrict__ Whh,   // [3072][1024]
    const float* __restrict__ Wdec,  // [256][1024]
    _Float16* __restrict__ Wws)      // [32][144][1024]
{
  int blk = blockIdx.x, tid = threadIdx.x;
  int k0 = tid * 4;
  if (blk < 768) {                      // dot blocks: rows rr<96 (s in 0..2), 4 rows each
    int cbv[4], rrv[4], jg[4], jh[4];
    #pragma unroll
    for (int rsel = 0; rsel < 4; ++rsel) {
      int dj = blk * 4 + rsel;
      int cb = dj / 96, rr = dj % 96;
      int s = rr >> 5, wcol = (rr >> 4) & 1, p = rr & 15;
      int j = cb * 32 + wcol * 16 + p;
      cbv[rsel] = cb; rrv[rsel] = rr;
      jg[rsel] = s * 1024 + j;
      jh[rsel] = (s == 0) ? j : (s == 1 ? 1024 + j : -1);
    }
    float acc[4][4];
    #pragma unroll
    for (int a = 0; a < 4; ++a) { acc[a][0]=0.f; acc[a][1]=0.f; acc[a][2]=0.f; acc[a][3]=0.f; }
    for (int q = 0; q < 256; ++q) {
      float4 wd = *(const float4*)(Wdec + (size_t)q * 1024 + k0);
      #pragma unroll
      for (int a = 0; a < 4; ++a) {
        float w = Wih[(size_t)jg[a] * 256 + q];
        acc[a][0] += w * wd.x; acc[a][1] += w * wd.y;
        acc[a][2] += w * wd.z; acc[a][3] += w * wd.w;
      }
    }
    #pragma unroll
    for (int a = 0; a < 4; ++a) {
      if (jh[a] >= 0) {
        const float* wh = Whh + (size_t)jh[a] * 1024 + k0;
        acc[a][0] += wh[0]; acc[a][1] += wh[1];
        acc[a][2] += wh[2]; acc[a][3] += wh[3];
      }
      _Float16* dst = Wws + ((size_t)cbv[a] * 144 + rrv[a]) * 1024 + k0;
      dst[0] = (_Float16)acc[a][0]; dst[1] = (_Float16)acc[a][1];
      dst[2] = (_Float16)acc[a][2]; dst[3] = (_Float16)acc[a][3];
    }
  } else {                              // copy blocks: rows rr in 96..143
    #pragma unroll
    for (int rsel = 0; rsel < 4; ++rsel) {
      int cr = (blk - 768) * 4 + rsel;
      int cb = cr / 48, rr = 96 + cr % 48;
      _Float16* dst = Wws + ((size_t)cb * 144 + rr) * 1024 + k0;
      if (rr < 128) {                   // s=3: Whh[2048+j]
        int j = cb * 32 + ((rr >> 4) & 1) * 16 + (rr & 15);
        const float* src = Whh + (size_t)(2048 + j) * 1024 + k0;
        dst[0] = (_Float16)src[0]; dst[1] = (_Float16)src[1];
        dst[2] = (_Float16)src[2]; dst[3] = (_Float16)src[3];
      } else if (rr < 136) {
        const float* src = Wdec + (size_t)(cb * 8 + rr - 128) * 1024 + k0;
        dst[0] = (_Float16)src[0]; dst[1] = (_Float16)src[1];
        dst[2] = (_Float16)src[2]; dst[3] = (_Float16)src[3];
      } else {
        dst[0] = (_Float16)0.f; dst[1] = (_Float16)0.f;
        dst[2] = (_Float16)0.f; dst[3] = (_Float16)0.f;
      }
    }
  }
}

__global__ __launch_bounds__(256) void prep_bias(
    const float* __restrict__ Wih,
    const float* __restrict__ bih, const float* __restrict__ bhh,
    const float* __restrict__ bdec_in,
    float* __restrict__ br, float* __restrict__ bz, float* __restrict__ bin_,
    float* __restrict__ bhn, float* __restrict__ bdec)
{
  int j = blockIdx.x * 256 + threadIdx.x;   // grid 4 -> j < 1024
  float bc0 = 0.f, bc1 = 0.f, bc2 = 0.f;
  for (int q = 0; q < 256; ++q) {
    float bd = bdec_in[q];
    bc0 += Wih[(size_t)j * 256 + q] * bd;
    bc1 += Wih[(size_t)(1024 + j) * 256 + q] * bd;
    bc2 += Wih[(size_t)(2048 + j) * 256 + q] * bd;
  }
  br[j]  = bih[j]        + bhh[j]        + bc0;
  bz[j]  = bih[1024 + j] + bhh[1024 + j] + bc1;
  bin_[j]= bih[2048 + j] + bc2;
  bhn[j] = bhh[2048 + j];
  if (j < 256) bdec[j] = bdec_in[j];
}

__global__ __launch_bounds__(256) void prep_h(
    const float* __restrict__ h0, _Float16* __restrict__ h16)
{
  int i = blockIdx.x * 256 + threadIdx.x;
  h16[i] = (_Float16)h0[i];
}

// ---------------- one GRU step (device fn, shared by both launch modes) ----------
// LDS (34816 B): A bufs 2x8192 @ 0/8192; B bufs 2x9216 @ 16384/25600.
// Per buffer: [row][4 kgroups of 16B], row stride 64 B; lds kgroup c holds
// global kgroup g = c ^ (r&3) (swizzle folded into DMA global address).
__device__ __forceinline__ void do_step(
    char* lds, int t, int mt, int cb, int tid,
    const _Float16* __restrict__ slab,
    const float* __restrict__ br, const float* __restrict__ bz,
    const float* __restrict__ bin_, const float* __restrict__ bhn,
    const float* __restrict__ bdec,
    const _Float16* __restrict__ hin16, const float* __restrict__ hin32,
    _Float16* __restrict__ hout16, float* __restrict__ hout32,
    float* __restrict__ out)
{
  const int wave = tid >> 6, lane = tid & 63;
  const int wr = wave >> 1, wc = wave & 1;
  const int col16 = lane & 15, quad = lane >> 4;
  const _Float16* __restrict__ Abase = hin16 + (size_t)mt * (128 * 1024);

  // DMA chunk geometry: chunk m covers row r=m>>2, lds-kgroup c=m&3,
  // global kgroup g = c ^ (r&3). Wave w issue j covers chunks (w*2+j)*64+lane.
  int offs[2];
  #pragma unroll
  for (int jj = 0; jj < 2; ++jj) {
    int m = (wave * 2 + jj) * 64 + lane;
    int r = m >> 2, g = (m & 3) ^ (r & 3);
    offs[jj] = r * 1024 + g * 8;
  }
  int offE;
  { int m = 512 + lane; int r = m >> 2, g = (m & 3) ^ (r & 3);
    offE = r * 1024 + g * 8; }         // B rows 128..143, wave 0 only

  const int swz = (quad ^ (col16 & 3)) << 4;   // ds_read column swizzle

  f32x4 accG[4][4]; f32x4 accD[2];
  const f32x4 fzero = {0.f, 0.f, 0.f, 0.f};
  #pragma unroll
  for (int i = 0; i < 4; ++i)
    #pragma unroll
    for (int jj = 0; jj < 4; ++jj) accG[i][jj] = fzero;
  accD[0] = fzero; accD[1] = fzero;

  auto issue_dma = [&](int bsel, int kc) {
    char* Ab = lds + bsel * 8192;
    char* Bb = lds + 16384 + bsel * 9216;
    #pragma unroll
    for (int jj = 0; jj < 2; ++jj) {
      gl_lds16(Abase + offs[jj] + kc, Ab + (wave * 2 + jj) * 1024);
      gl_lds16(slab  + offs[jj] + kc, Bb + (wave * 2 + jj) * 1024);
    }
    if (wave == 0)
      gl_lds16(slab + offE + kc, Bb + 8192);
  };

  issue_dma(0, 0);
  __syncthreads();                     // drains DMA(buf0)

  #pragma unroll 1
  for (int ki = 0; ki < 32; ++ki) {
    const int cur = ki & 1;
    if (ki < 31) issue_dma(cur ^ 1, (ki + 1) * 32);   // lands during MFMA phase
    const char* As = lds + cur * 8192;
    const char* Bs = lds + 16384 + cur * 9216;

    f16x8 af[4], ad2[2], bg[4], bdv;
    #pragma unroll
    for (int fm = 0; fm < 4; ++fm)
      af[fm] = *(const f16x8*)(As + (64 * wr + 16 * fm + col16) * 64 + swz);
    #pragma unroll
    for (int d = 0; d < 2; ++d)
      ad2[d] = *(const f16x8*)(As + (32 * wave + 16 * d + col16) * 64 + swz);
    #pragma unroll
    for (int fn = 0; fn < 4; ++fn)
      bg[fn] = *(const f16x8*)(Bs + (32 * fn + 16 * wc + col16) * 64 + swz);
    bdv = *(const f16x8*)(Bs + (128 + col16) * 64 + swz);

    #pragma unroll
    for (int fm = 0; fm < 4; ++fm)
      #pragma unroll
      for (int fn = 0; fn < 4; ++fn)
        accG[fm][fn] = __builtin_amdgcn_mfma_f32_16x16x32_f16(af[fm], bg[fn], accG[fm][fn], 0, 0, 0);
    accD[0] = __builtin_amdgcn_mfma_f32_16x16x32_f16(ad2[0], bdv, accD[0], 0, 0, 0);
    accD[1] = __builtin_amdgcn_mfma_f32_16x16x32_f16(ad2[1], bdv, accD[1], 0, 0, 0);
    __syncthreads();                   // next-buf DMA drained here (overlapped)
  }

  // epilogue: gate math in registers (C/D: n = lane&15, m = quad*4 + reg)
  if (t < TS) {
    const int j = cb * 32 + wc * 16 + col16;       // gate col 0..1023
    const float vbr = br[j], vbz = bz[j], vbi = bin_[j], vbh = bhn[j];
    #pragma unroll
    for (int fm = 0; fm < 4; ++fm) {
      const int mbase = mt * 128 + 64 * wr + 16 * fm + quad * 4;
      #pragma unroll
      for (int ri = 0; ri < 4; ++ri) {
        const int m = mbase + ri;
        float rg = 1.f / (1.f + __expf(-(accG[fm][0][ri] + vbr)));
        float zg = 1.f / (1.f + __expf(-(accG[fm][1][ri] + vbz)));
        float nn = tanhf(accG[fm][2][ri] + vbi + rg * (accG[fm][3][ri] + vbh));
        float hold = hin32[(size_t)m * 1024 + j];
        float hnew = (1.f - zg) * nn + zg * hold;
        hout32[(size_t)m * 1024 + j] = hnew;
        hout16[(size_t)m * 1024 + j] = (_Float16)hnew;
      }
    }
  }
  if (t > 0 && col16 < 8) {            // decode of h_t -> out[:, t-1, :]
    const int oc = cb * 8 + col16;
    const float vb = bdec[oc];
    #pragma unroll
    for (int d = 0; d < 2; ++d) {
      const int mbase = mt * 128 + 32 * wave + 16 * d + quad * 4;
      #pragma unroll
      for (int ri = 0; ri < 4; ++ri) {
        const int m = mbase + ri;
        out[(size_t)m * (TS * OD) + (size_t)(t - 1) * OD + oc] = accD[d][ri] + vb;
      }
    }
  }
}

// ---------------- persistent fused kernel (cooperative) ----------------
// Cross-step sync: flags[t][mt] counts (mt,*) blocks done with step t.
// Writer: stores -> __syncthreads (vmcnt drain) -> tid0 release-fence + add.
// Reader: lane0-of-each-wave relaxed spin to 32 -> per-wave acquire fence.
__global__ __launch_bounds__(256, 1) void fused_steps(
    const _Float16* __restrict__ Wws,
    const float* __restrict__ br, const float* __restrict__ bz,
    const float* __restrict__ bin_, const float* __restrict__ bhn,
    const float* __restrict__ bdec,
    const float* __restrict__ h0_32,
    _Float16* __restrict__ h16A, _Float16* __restrict__ h16B,
    float* __restrict__ h32A, float* __restrict__ h32B,
    float* __restrict__ out, int* flags)
{
  __shared__ __align__(16) char lds[2 * 8192 + 2 * 9216];   // 34816 B
  const int tid = threadIdx.x;
  const int lane = tid & 63;
  const int mt = blockIdx.x >> 5, cb = blockIdx.x & 31;
  const _Float16* __restrict__ slab = Wws + (size_t)cb * (144 * 1024);

  #pragma unroll 1
  for (int t = 0; t <= TS; ++t) {
    if (t > 0) {                       // wait for row-stripe mt of step t-1
      const int* fl = flags + (t - 1) * 8 + mt;
      if (lane == 0) {
        while (__hip_atomic_load(fl, __ATOMIC_RELAXED, __HIP_MEMORY_SCOPE_AGENT) < 32)
          __builtin_amdgcn_s_sleep(1);
      }
      __builtin_amdgcn_fence(__ATOMIC_ACQUIRE, "agent");
    }

    const _Float16* hin16 = (t & 1) ? h16B : h16A;
    const float*    hin32 = (t == 0) ? h0_32 : ((t & 1) ? h32B : h32A);
    _Float16*       hout16 = (t & 1) ? h16A : h16B;
    float*          hout32 = (t & 1) ? h32A : h32B;

    do_step(lds, t, mt, cb, tid, slab, br, bz, bin_, bhn, bdec,
            hin16, hin32, hout16, hout32, out);

    if (t < TS) {                      // publish this block's h tiles for step t
      __syncthreads();                 // all waves' stores vmcnt-drained
      if (tid == 0) {
        __builtin_amdgcn_fence(__ATOMIC_RELEASE, "agent");
        __hip_atomic_fetch_add(flags + t * 8 + mt, 1,
                               __ATOMIC_RELAXED, __HIP_MEMORY_SCOPE_AGENT);
      }
    }
  }
}

// ---------------- per-step fallback (normal launch) ----------------
__global__ __launch_bounds__(256, 1) void step_kernel(
    const _Float16* __restrict__ Wws,
    const float* __restrict__ br, const float* __restrict__ bz,
    const float* __restrict__ bin_, const float* __restrict__ bhn,
    const float* __restrict__ bdec,
    const _Float16* __restrict__ hin16, const float* __restrict__ hin32,
    _Float16* __restrict__ hout16, float* __restrict__ hout32,
    float* __restrict__ out, int t)
{
  __shared__ __align__(16) char lds[2 * 8192 + 2 * 9216];
  const int tid = threadIdx.x;
  const int mt = blockIdx.x >> 5, cb = blockIdx.x & 31;
  const _Float16* __restrict__ slab = Wws + (size_t)cb * (144 * 1024);
  do_step(lds, t, mt, cb, tid, slab, br, bz, bin_, bhn, bdec,
          hin16, hin32, hout16, hout32, out);
}

extern "C" void kernel_launch(void* const* d_in, const int* in_sizes, int n_in,
                              void* d_out, int out_size, void* d_ws, size_t ws_size,
                              hipStream_t stream) {
  const float* h0      = (const float*)d_in[0];   // [1,1024,1024]
  const float* Wih     = (const float*)d_in[1];   // [3072,256]
  const float* Whh     = (const float*)d_in[2];   // [3072,1024]
  const float* bih     = (const float*)d_in[3];   // [3072]
  const float* bhh     = (const float*)d_in[4];   // [3072]
  const float* Wdec    = (const float*)d_in[5];   // [256,1024]
  const float* bdec_in = (const float*)d_in[6];   // [256]
  float* outp = (float*)d_out;                    // [1024,128,256] fp32

  char* ws = (char*)d_ws;
  _Float16* Wws = (_Float16*)ws;                         // 9,437,184 B
  float* br   = (float*)(ws + 9437184);
  float* bz   = (float*)(ws + 9437184 + 4096);
  float* bin_ = (float*)(ws + 9437184 + 8192);
  float* bhn  = (float*)(ws + 9437184 + 12288);
  float* bdec = (float*)(ws + 9437184 + 16384);
  float* h32A = (float*)(ws + 9461760);                  // 4 MB
  float* h32B = h32A + 1024 * 1024;                      // 4 MB
  _Float16* h16A = (_Float16*)(ws + 9461760 + 8388608);  // 2 MB
  _Float16* h16B = h16A + 1024 * 1024;                   // 2 MB
  int* flags = (int*)(ws + 9461760 + 8388608 + 4194304); // TS*8 ints
  // total ws use ~22.05 MB

  prep_w<<<1152, 256, 0, stream>>>(Wih, Whh, Wdec, Wws);
  prep_bias<<<4, 256, 0, stream>>>(Wih, bih, bhh, bdec_in, br, bz, bin_, bhn, bdec);
  prep_h<<<4096, 256, 0, stream>>>(h0, h16A);
  hipMemsetAsync(flags, 0, TS * 8 * sizeof(int), stream);

  void* args[] = {
    (void*)&Wws, (void*)&br, (void*)&bz, (void*)&bin_, (void*)&bhn, (void*)&bdec,
    (void*)&h0, (void*)&h16A, (void*)&h16B, (void*)&h32A, (void*)&h32B,
    (void*)&outp, (void*)&flags
  };
  hipError_t e = hipLaunchCooperativeKernel((const void*)fused_steps, dim3(256),
                                            dim3(256), args, 0, stream);
  if (e != hipSuccess) {               // fallback: per-step launches (proven path)
    for (int t = 0; t <= TS; ++t) {
      const _Float16* in16 = (t & 1) ? h16B : h16A;
      const float*    in32 = (t == 0) ? h0 : ((t & 1) ? h32B : h32A);
      _Float16*       o16  = (t & 1) ? h16A : h16B;
      float*          o32  = (t & 1) ? h32A : h32B;
      step_kernel<<<256, 256, 0, stream>>>(Wws, br, bz, bin_, bhn, bdec,
                                           in16, in32, o16, o32, outp, t);
    }
  }
}